// Round 2
// baseline (176.193 us; speedup 1.0000x reference)
//
#include <hip/hip_runtime.h>

#define WW 512
#define HH 512
#define NPLANES 64   // B*C = 16*4
#define NCH 4
#define NSTRIP 8     // 64-row strips per plane (4 waves x 16 rows per block)

// sigmoid((x - 0.5) * 10) = 1 / (1 + exp2(-x*10*log2e + 5*log2e))
__device__ __forceinline__ float sigf(float x) {
    float e = __builtin_amdgcn_exp2f(__builtin_fmaf(x, -14.4269504089f, 7.2134752044f));
    return __builtin_amdgcn_rcpf(1.0f + e);
}

// Stage 1 with 2-deep row prefetch.
// R1 lesson: occupancy 34->63% left dur/VALUBusy/HBM invariant -- waves convoy:
// all issue loads, all stall ~500cy at the conversion vmcnt, all compute, repeat.
// Fix: load consumed at iter r is issued at iter r-2 (~2000cy earlier) so the
// vmcnt wait is already satisfied; ping-pong buffers A/B, full unroll so the
// prev/cur/nxt rotation is pure register renaming.
__global__ __launch_bounds__(256, 4)
void k_stage1(const float* __restrict__ inp, const float* __restrict__ tgt,
              float* __restrict__ colpart, float* __restrict__ rowsum8,
              float* __restrict__ out) {
    const int bid    = blockIdx.x;
    const int tensor = bid >> 9;          // 0..1
    const int plane  = (bid >> 3) & 63;   // 0..63
    const int s      = bid & 7;           // 0..7 (64-row strip)
    const int tid    = threadIdx.x;
    const int wave   = tid >> 6;          // 0..3
    const int lane   = tid & 63;

    if (bid == 0 && tid == 0) out[0] = 0.0f;  // zero-init for stage-2 atomics

    const float* __restrict__ base =
        (tensor == 0 ? inp : tgt) + (size_t)plane * (HH * WW);
    const int r0    = s * 64 + wave * 16;
    const int cbase = lane * 8;

    float prev[8], cur[8], cacc[8];
    #pragma unroll
    for (int k = 0; k < 8; ++k) cacc[k] = 0.0f;

    // prologue: prev = sig(row r0-1) (zero-pad), cur = sig(row r0)
    if (r0 == 0) {
        #pragma unroll
        for (int k = 0; k < 8; ++k) prev[k] = 0.0f;
    } else {
        const float4* p4 = reinterpret_cast<const float4*>(base + (size_t)(r0 - 1) * WW + cbase);
        float4 a = p4[0], b = p4[1];
        prev[0]=sigf(a.x); prev[1]=sigf(a.y); prev[2]=sigf(a.z); prev[3]=sigf(a.w);
        prev[4]=sigf(b.x); prev[5]=sigf(b.y); prev[6]=sigf(b.z); prev[7]=sigf(b.w);
    }
    {
        const float4* p4 = reinterpret_cast<const float4*>(base + (size_t)r0 * WW + cbase);
        float4 a = p4[0], b = p4[1];
        cur[0]=sigf(a.x); cur[1]=sigf(a.y); cur[2]=sigf(a.z); cur[3]=sigf(a.w);
        cur[4]=sigf(b.x); cur[5]=sigf(b.y); cur[6]=sigf(b.z); cur[7]=sigf(b.w);
    }

    // 2-deep prefetch: A = raw row r0+1, B = raw row r0+2 (both always < HH,
    // since max r0 = 496 -> 498)
    float4 A0, A1, B0, B1;
    {
        const float4* p4 = reinterpret_cast<const float4*>(base + (size_t)(r0 + 1) * WW + cbase);
        A0 = p4[0]; A1 = p4[1];
    }
    {
        const float4* p4 = reinterpret_cast<const float4*>(base + (size_t)(r0 + 2) * WW + cbase);
        B0 = p4[0]; B1 = p4[1];
    }

    float* __restrict__ rs_out =
        rowsum8 + ((size_t)tensor * NPLANES + plane) * (HH * 8);

    // body for one row r: consumes raw buffer (X0,X1) = row r+1,
    // then refills it with row r+3.
#define ITER_BODY(r, X0, X1)                                                   \
    {                                                                          \
        /* horizontal bounds on row r (edge vals cross-lane) */                \
        float lv = __shfl_up(cur[7], 1);                                       \
        if (lane == 0)  lv = 0.0f;                                             \
        float rv = __shfl_down(cur[0], 1);                                     \
        if (lane == 63) rv = 0.0f;                                             \
        float hp = sigf(fabsf(cur[1] - lv));                                   \
        _Pragma("unroll")                                                      \
        for (int k = 1; k < 7; ++k)                                            \
            hp += sigf(fabsf(cur[k + 1] - cur[k - 1]));                        \
        hp += sigf(fabsf(rv - cur[6]));                                        \
        hp += __shfl_xor(hp, 8);                                               \
        hp += __shfl_xor(hp, 16);                                              \
        hp += __shfl_xor(hp, 32);                                              \
        if (lane < 8) rs_out[(size_t)(r) * 8 + lane] = hp;                     \
        /* convert raw row r+1 (loaded 2 iters ago) */                         \
        float nxt[8];                                                          \
        if ((r) + 1 < HH) {                                                    \
            nxt[0]=sigf(X0.x); nxt[1]=sigf(X0.y); nxt[2]=sigf(X0.z); nxt[3]=sigf(X0.w); \
            nxt[4]=sigf(X1.x); nxt[5]=sigf(X1.y); nxt[6]=sigf(X1.z); nxt[7]=sigf(X1.w); \
        } else {                                                               \
            _Pragma("unroll")                                                  \
            for (int k = 0; k < 8; ++k) nxt[k] = 0.0f;                         \
        }                                                                      \
        /* refill buffer with row r+3 (consumed 2 iters from now) */           \
        if ((r) + 3 < HH) {                                                    \
            const float4* p4 = reinterpret_cast<const float4*>(               \
                base + (size_t)((r) + 3) * WW + cbase);                        \
            X0 = p4[0]; X1 = p4[1];                                            \
        }                                                                      \
        /* vertical bounds + rotate window */                                  \
        _Pragma("unroll")                                                      \
        for (int k = 0; k < 8; ++k) {                                          \
            cacc[k] += sigf(fabsf(nxt[k] - prev[k]));                          \
            prev[k] = cur[k];                                                  \
            cur[k]  = nxt[k];                                                  \
        }                                                                      \
    }

    #pragma unroll
    for (int i = 0; i < 16; i += 2) {
        ITER_BODY(r0 + i,     A0, A1)   // even: consumes/refills A
        ITER_BODY(r0 + i + 1, B0, B1)   // odd:  consumes/refills B
    }
#undef ITER_BODY

    // combine column partials across the 4 waves of this block
    __shared__ float cl[4][WW];
    #pragma unroll
    for (int k = 0; k < 8; ++k) cl[wave][cbase + k] = cacc[k];
    __syncthreads();

    float* __restrict__ cp_out =
        colpart + (((size_t)tensor * NPLANES + plane) * NSTRIP + s) * WW;
    for (int c = tid; c < WW; c += 256)
        cp_out[c] = cl[0][c] + cl[1][c] + cl[2][c] + cl[3][c];
}

// logical sobel-source value: S(0)=512*sig(0), S(j)=sum[j-1], 0 outside [0,512)
__device__ __forceinline__ float Sval(const float* s, int j, float s0) {
    if (j < 0 || j >= 512) return 0.0f;
    if (j == 0) return s0;
    return s[j - 1];
}
__device__ __forceinline__ float term(const float* s, int j, float s0) {
    return fabsf(Sval(s, j + 1, s0) - Sval(s, j - 1, s0));
}

// Stage 2 (merged with mean): one block per plane; finalize col/row sums,
// sobel+abs+sum both directions for both tensors, atomicAdd mean contribution.
__global__ __launch_bounds__(256)
void k_stage2(const float* __restrict__ colpart, const float* __restrict__ rowsum8,
              const float* __restrict__ weight, float* __restrict__ out) {
    __shared__ float cI[WW], cT[WW], rI[WW], rT[WW];
    const int p   = blockIdx.x;   // plane = b*4 + c
    const int tid = threadIdx.x;

    for (int c = tid; c < WW; c += 256) {
        const float* a = colpart + (((size_t)0 * NPLANES + p) * NSTRIP) * WW + c;
        const float* b = colpart + (((size_t)1 * NPLANES + p) * NSTRIP) * WW + c;
        float sa = 0.f, sb = 0.f;
        #pragma unroll
        for (int i = 0; i < NSTRIP; ++i) { sa += a[i * WW]; sb += b[i * WW]; }
        cI[c] = sa;
        cT[c] = sb;
        const float* ra = rowsum8 + ((size_t)0 * NPLANES + p) * (HH * 8) + (size_t)c * 8;
        const float* rb = rowsum8 + ((size_t)1 * NPLANES + p) * (HH * 8) + (size_t)c * 8;
        float sra = 0.f, srb = 0.f;
        #pragma unroll
        for (int i = 0; i < 8; ++i) { sra += ra[i]; srb += rb[i]; }
        rI[c] = sra;
        rT[c] = srb;
    }
    __syncthreads();

    // 512 * sigmoid(-5)
    const float s0 = 3.4267396732f;

    float sIx = 0.f, sTx = 0.f, sIy = 0.f, sTy = 0.f;
    for (int j = tid; j < WW; j += 256) {
        sIx += term(cI, j, s0);
        sTx += term(cT, j, s0);
        sIy += term(rI, j, s0);
        sTy += term(rT, j, s0);
    }
    #pragma unroll
    for (int off = 32; off >= 1; off >>= 1) {
        sIx += __shfl_xor(sIx, off);
        sTx += __shfl_xor(sTx, off);
        sIy += __shfl_xor(sIy, off);
        sTy += __shfl_xor(sTy, off);
    }
    __shared__ float red[4][4];
    const int wave = tid >> 6, lane = tid & 63;
    if (lane == 0) {
        red[wave][0] = sIx; red[wave][1] = sTx;
        red[wave][2] = sIy; red[wave][3] = sTy;
    }
    __syncthreads();
    if (tid == 0) {
        float Ix = 0.f, Tx = 0.f, Iy = 0.f, Ty = 0.f;
        for (int w2 = 0; w2 < 4; ++w2) {
            Ix += red[w2][0]; Tx += red[w2][1];
            Iy += red[w2][2]; Ty += red[w2][3];
        }
        Ix *= 0.25f; Tx *= 0.25f; Iy *= 0.25f; Ty *= 0.25f;
        const float wgt = weight[p & (NCH - 1)];
        float loss = 0.5f * (fabsf((Ix - Tx) * wgt) + fabsf((Iy - Ty) * wgt));
        atomicAdd(out, loss * (1.0f / NPLANES));
    }
}

extern "C" void kernel_launch(void* const* d_in, const int* in_sizes, int n_in,
                              void* d_out, int out_size, void* d_ws, size_t ws_size,
                              hipStream_t stream) {
    const float* inp = (const float*)d_in[0];
    const float* tgt = (const float*)d_in[1];
    const float* wgt = (const float*)d_in[2];
    float* ws = (float*)d_ws;

    // ws layout (floats):
    float* colpart = ws;                       // [2][64][8][512]  = 524288
    float* rowsum8 = ws + 524288;              // [2][64][512][8]  = 524288

    k_stage1<<<1024, 256, 0, stream>>>(inp, tgt, colpart, rowsum8, (float*)d_out);
    k_stage2<<<64, 256, 0, stream>>>(colpart, rowsum8, wgt, (float*)d_out);
}

// Round 3
// 154.005 us; speedup vs baseline: 1.1441x; 1.1441x over previous
//
#include <hip/hip_runtime.h>

#define WW 512
#define HH 512
#define NPLANES 64   // B*C = 16*4
#define NCH 4
#define NSTRIP 8     // 64-row strips per plane (4 waves x 16 rows per block)

// e(x) = 2^(-14.43*x + 7.21); sigmoid((x-0.5)*10) = 1/(1+e(x))
__device__ __forceinline__ float expu(float x) {
    return __builtin_amdgcn_exp2f(__builtin_fmaf(x, -14.4269504089f, 7.2134752044f));
}
__device__ __forceinline__ float sigf(float x) {          // prologue only
    return __builtin_amdgcn_rcpf(1.0f + expu(x));
}
// sum of 1/p_i over 4 values with ONE rcp:
//   (p0+p1)/(p0 p1) + (p2+p3)/(p2 p3)
__device__ __forceinline__ float sum4sig(float p0, float p1, float p2, float p3) {
    float q01 = p0 * p1, q23 = p2 * p3;
    float inv = __builtin_amdgcn_rcpf(q01 * q23);
    return __builtin_fmaf(p0 + p1, q23, (p2 + p3) * q01) * inv;
}
// individual reciprocals of 4 values with ONE rcp (batch inversion)
__device__ __forceinline__ void inv4(float p0, float p1, float p2, float p3,
                                     float& r0, float& r1, float& r2, float& r3) {
    float q01 = p0 * p1, q23 = p2 * p3;
    float inv = __builtin_amdgcn_rcpf(q01 * q23);
    float i01 = q23 * inv, i23 = q01 * inv;   // 1/(p0 p1), 1/(p2 p3)
    r0 = p1 * i01; r1 = p0 * i01;
    r2 = p3 * i23; r3 = p2 * i23;
}

// Stage 1: R0 structure (4 waves x 16 rows, 1-deep load-ahead) with the trans
// pipe decongested: rcp per row-iter 24 -> 6 via batch-reciprocal algebra.
// R1 lesson: occupancy 34->63% changed nothing -> not latency/wave-count bound.
// R2 lesson: deep unroll spilled (WRITE_SIZE 4.6->44.5 MB scratch) -> keep
// rolled loop, scalar temporaries only.
__global__ __launch_bounds__(256, 4)
void k_stage1(const float* __restrict__ inp, const float* __restrict__ tgt,
              float* __restrict__ colpart, float* __restrict__ rowsum8,
              float* __restrict__ out) {
    const int bid    = blockIdx.x;
    const int tensor = bid >> 9;          // 0..1
    const int plane  = (bid >> 3) & 63;   // 0..63
    const int s      = bid & 7;           // 0..7 (64-row strip)
    const int tid    = threadIdx.x;
    const int wave   = tid >> 6;          // 0..3
    const int lane   = tid & 63;

    if (bid == 0 && tid == 0) out[0] = 0.0f;  // zero-init for stage-2 atomics

    const float* __restrict__ base =
        (tensor == 0 ? inp : tgt) + (size_t)plane * (HH * WW);
    const int r0    = s * 64 + wave * 16;
    const int r1    = r0 + 16;
    const int cbase = lane * 8;

    float prev[8], cur[8], cacc[8];
    #pragma unroll
    for (int k = 0; k < 8; ++k) cacc[k] = 0.0f;

    // prologue: prev = sig(row r0-1) (zero-pad), cur = sig(row r0)
    if (r0 == 0) {
        #pragma unroll
        for (int k = 0; k < 8; ++k) prev[k] = 0.0f;
    } else {
        const float4* p4 = reinterpret_cast<const float4*>(base + (size_t)(r0 - 1) * WW + cbase);
        float4 a = p4[0], b = p4[1];
        prev[0]=sigf(a.x); prev[1]=sigf(a.y); prev[2]=sigf(a.z); prev[3]=sigf(a.w);
        prev[4]=sigf(b.x); prev[5]=sigf(b.y); prev[6]=sigf(b.z); prev[7]=sigf(b.w);
    }
    {
        const float4* p4 = reinterpret_cast<const float4*>(base + (size_t)r0 * WW + cbase);
        float4 a = p4[0], b = p4[1];
        cur[0]=sigf(a.x); cur[1]=sigf(a.y); cur[2]=sigf(a.z); cur[3]=sigf(a.w);
        cur[4]=sigf(b.x); cur[5]=sigf(b.y); cur[6]=sigf(b.z); cur[7]=sigf(b.w);
    }

    float* __restrict__ rs_out =
        rowsum8 + ((size_t)tensor * NPLANES + plane) * (HH * 8);

    // strength-reduced row pointer for the (r+1) load
    const float* rowp = base + (size_t)(r0 + 1) * WW + cbase;

    for (int r = r0; r < r1; ++r, rowp += WW) {
        // 1) issue next-row loads FIRST (raw; convert later)
        float4 a, b;
        if (r + 1 < HH) {
            const float4* p4 = reinterpret_cast<const float4*>(rowp);
            a = p4[0]; b = p4[1];
        } else {
            a = make_float4(0.f,0.f,0.f,0.f); b = a;
        }

        // 2) horizontal bounds on row r (edge vals cross-lane); row sum needs
        //    only the SUM of 8 sigmoids -> 8 exp + 2 rcp (was 8 exp + 8 rcp)
        float lv = __shfl_up(cur[7], 1);
        if (lane == 0)  lv = 0.0f;   // zero-pad col -1
        float rv = __shfl_down(cur[0], 1);
        if (lane == 63) rv = 0.0f;   // zero-pad col W

        float h0 = 1.0f + expu(fabsf(cur[1] - lv));
        float h1 = 1.0f + expu(fabsf(cur[2] - cur[0]));
        float h2 = 1.0f + expu(fabsf(cur[3] - cur[1]));
        float h3 = 1.0f + expu(fabsf(cur[4] - cur[2]));
        float h4 = 1.0f + expu(fabsf(cur[5] - cur[3]));
        float h5 = 1.0f + expu(fabsf(cur[6] - cur[4]));
        float h6 = 1.0f + expu(fabsf(cur[7] - cur[5]));
        float h7 = 1.0f + expu(fabsf(rv     - cur[6]));
        float hp = sum4sig(h0, h1, h2, h3) + sum4sig(h4, h5, h6, h7);

        // 3-step butterfly: lanes 0..7 hold 8 partials covering the full row.
        hp += __shfl_xor(hp, 8);
        hp += __shfl_xor(hp, 16);
        hp += __shfl_xor(hp, 32);
        if (lane < 8) rs_out[(size_t)r * 8 + lane] = hp;

        // 3) convert loaded row via batch inversion: 8 exp + 2 rcp (was +8 rcp)
        float nxt[8];
        if (r + 1 < HH) {
            float p0 = 1.0f + expu(a.x), p1 = 1.0f + expu(a.y);
            float p2 = 1.0f + expu(a.z), p3 = 1.0f + expu(a.w);
            float p4_ = 1.0f + expu(b.x), p5 = 1.0f + expu(b.y);
            float p6 = 1.0f + expu(b.z), p7 = 1.0f + expu(b.w);
            inv4(p0, p1, p2, p3, nxt[0], nxt[1], nxt[2], nxt[3]);
            inv4(p4_, p5, p6, p7, nxt[4], nxt[5], nxt[6], nxt[7]);
        } else {
            #pragma unroll
            for (int k = 0; k < 8; ++k) nxt[k] = 0.0f;  // zero-pad row H
        }

        // 4) vertical bounds: individual values per column accumulator;
        //    batch inversion again: 8 exp + 2 rcp (was 8 rcp)
        {
            float v0 = 1.0f + expu(fabsf(nxt[0] - prev[0]));
            float v1 = 1.0f + expu(fabsf(nxt[1] - prev[1]));
            float v2 = 1.0f + expu(fabsf(nxt[2] - prev[2]));
            float v3 = 1.0f + expu(fabsf(nxt[3] - prev[3]));
            float v4 = 1.0f + expu(fabsf(nxt[4] - prev[4]));
            float v5 = 1.0f + expu(fabsf(nxt[5] - prev[5]));
            float v6 = 1.0f + expu(fabsf(nxt[6] - prev[6]));
            float v7 = 1.0f + expu(fabsf(nxt[7] - prev[7]));
            float s0, s1, s2, s3, s4, s5, s6, s7;
            inv4(v0, v1, v2, v3, s0, s1, s2, s3);
            inv4(v4, v5, v6, v7, s4, s5, s6, s7);
            cacc[0] += s0; cacc[1] += s1; cacc[2] += s2; cacc[3] += s3;
            cacc[4] += s4; cacc[5] += s5; cacc[6] += s6; cacc[7] += s7;
        }

        // rotate window
        #pragma unroll
        for (int k = 0; k < 8; ++k) { prev[k] = cur[k]; cur[k] = nxt[k]; }
    }

    // combine column partials across the 4 waves of this block
    __shared__ float cl[4][WW];
    #pragma unroll
    for (int k = 0; k < 8; ++k) cl[wave][cbase + k] = cacc[k];
    __syncthreads();

    float* __restrict__ cp_out =
        colpart + (((size_t)tensor * NPLANES + plane) * NSTRIP + s) * WW;
    for (int c = tid; c < WW; c += 256)
        cp_out[c] = cl[0][c] + cl[1][c] + cl[2][c] + cl[3][c];
}

// logical sobel-source value: S(0)=512*sig(0), S(j)=sum[j-1], 0 outside [0,512)
__device__ __forceinline__ float Sval(const float* s, int j, float s0) {
    if (j < 0 || j >= 512) return 0.0f;
    if (j == 0) return s0;
    return s[j - 1];
}
__device__ __forceinline__ float term(const float* s, int j, float s0) {
    return fabsf(Sval(s, j + 1, s0) - Sval(s, j - 1, s0));
}

// Stage 2 (merged with mean): one block per plane; finalize col/row sums,
// sobel+abs+sum both directions for both tensors, atomicAdd mean contribution.
__global__ __launch_bounds__(256)
void k_stage2(const float* __restrict__ colpart, const float* __restrict__ rowsum8,
              const float* __restrict__ weight, float* __restrict__ out) {
    __shared__ float cI[WW], cT[WW], rI[WW], rT[WW];
    const int p   = blockIdx.x;   // plane = b*4 + c
    const int tid = threadIdx.x;

    for (int c = tid; c < WW; c += 256) {
        const float* a = colpart + (((size_t)0 * NPLANES + p) * NSTRIP) * WW + c;
        const float* b = colpart + (((size_t)1 * NPLANES + p) * NSTRIP) * WW + c;
        float sa = 0.f, sb = 0.f;
        #pragma unroll
        for (int i = 0; i < NSTRIP; ++i) { sa += a[i * WW]; sb += b[i * WW]; }
        cI[c] = sa;
        cT[c] = sb;
        const float* ra = rowsum8 + ((size_t)0 * NPLANES + p) * (HH * 8) + (size_t)c * 8;
        const float* rb = rowsum8 + ((size_t)1 * NPLANES + p) * (HH * 8) + (size_t)c * 8;
        float sra = 0.f, srb = 0.f;
        #pragma unroll
        for (int i = 0; i < 8; ++i) { sra += ra[i]; srb += rb[i]; }
        rI[c] = sra;
        rT[c] = srb;
    }
    __syncthreads();

    // 512 * sigmoid(-5)
    const float s0 = 3.4267396732f;

    float sIx = 0.f, sTx = 0.f, sIy = 0.f, sTy = 0.f;
    for (int j = tid; j < WW; j += 256) {
        sIx += term(cI, j, s0);
        sTx += term(cT, j, s0);
        sIy += term(rI, j, s0);
        sTy += term(rT, j, s0);
    }
    #pragma unroll
    for (int off = 32; off >= 1; off >>= 1) {
        sIx += __shfl_xor(sIx, off);
        sTx += __shfl_xor(sTx, off);
        sIy += __shfl_xor(sIy, off);
        sTy += __shfl_xor(sTy, off);
    }
    __shared__ float red[4][4];
    const int wave = tid >> 6, lane = tid & 63;
    if (lane == 0) {
        red[wave][0] = sIx; red[wave][1] = sTx;
        red[wave][2] = sIy; red[wave][3] = sTy;
    }
    __syncthreads();
    if (tid == 0) {
        float Ix = 0.f, Tx = 0.f, Iy = 0.f, Ty = 0.f;
        for (int w2 = 0; w2 < 4; ++w2) {
            Ix += red[w2][0]; Tx += red[w2][1];
            Iy += red[w2][2]; Ty += red[w2][3];
        }
        Ix *= 0.25f; Tx *= 0.25f; Iy *= 0.25f; Ty *= 0.25f;
        const float wgt = weight[p & (NCH - 1)];
        float loss = 0.5f * (fabsf((Ix - Tx) * wgt) + fabsf((Iy - Ty) * wgt));
        atomicAdd(out, loss * (1.0f / NPLANES));
    }
}

extern "C" void kernel_launch(void* const* d_in, const int* in_sizes, int n_in,
                              void* d_out, int out_size, void* d_ws, size_t ws_size,
                              hipStream_t stream) {
    const float* inp = (const float*)d_in[0];
    const float* tgt = (const float*)d_in[1];
    const float* wgt = (const float*)d_in[2];
    float* ws = (float*)d_ws;

    // ws layout (floats):
    float* colpart = ws;                       // [2][64][8][512]  = 524288
    float* rowsum8 = ws + 524288;              // [2][64][512][8]  = 524288

    k_stage1<<<1024, 256, 0, stream>>>(inp, tgt, colpart, rowsum8, (float*)d_out);
    k_stage2<<<64, 256, 0, stream>>>(colpart, rowsum8, wgt, (float*)d_out);
}